// Round 5
// baseline (3091.865 us; speedup 1.0000x reference)
//
#include <hip/hip_runtime.h>
#include <hip/hip_bf16.h>
#include <cstdint>
#include <cstddef>

#define B_ 128
#define T_ 100
#define D_ 2048
#define H_ 1024
#define O_ 20
#define H2 512

#define GEMM_NB 800   // 100 t-slabs x 8 n-tiles
#define XI_READY 8    // n-tiles per slab
#define GRID_NB 1600  // 512 (256 p2 + 256 gemm) + 1088 (544 gemm + 544 filler)

typedef float vfloat4 __attribute__((ext_vector_type(4)));  // native vec for NT st

__device__ inline void f4acc(float4& a, const float4 v) {
    a.x += v.x; a.y += v.y; a.z += v.z; a.w += v.w;
}

// ---------------------------------------------------------------------------
// prep: W2oT[h][o] = Wh2o[o][h]; zero nbr accumulators, pair flags, xi flags.
// ---------------------------------------------------------------------------
__global__ __launch_bounds__(256) void prep_kernel(const float* __restrict__ Wh2o,
                                                   float* __restrict__ W2oT,
                                                   float* __restrict__ nbr,
                                                   int* __restrict__ g_flag,
                                                   int* __restrict__ xi_done)
{
    int i = blockIdx.x * 256 + threadIdx.x;
    if (i < H_ * O_) {
        int hh = i / O_;
        int oo = i - hh * O_;
        W2oT[i] = Wh2o[oo * H_ + hh];
    }
    if (i < T_) { nbr[i] = 0.0f; xi_done[i] = 0; }
    if (i < B_ * 2) g_flag[i] = 0;
}

// ---------------------------------------------------------------------------
// transpose Wh2h[h][j] -> WT[j][h]
// ---------------------------------------------------------------------------
__global__ __launch_bounds__(256) void transpose_kernel(const float* __restrict__ A,
                                                        float* __restrict__ AT)
{
    __shared__ float tile[32][33];
    int bx = blockIdx.x * 32, by = blockIdx.y * 32;
    int tx = threadIdx.x, ty = threadIdx.y;  // block (32,8)
#pragma unroll
    for (int i = 0; i < 32; i += 8)
        tile[ty + i][tx] = A[(size_t)(by + ty + i) * H_ + bx + tx];
    __syncthreads();
#pragma unroll
    for (int i = 0; i < 32; i += 8)
        AT[(size_t)(bx + ty + i) * H_ + by + tx] = tile[tx][ty + i];
}

// ---------------------------------------------------------------------------
// GEMM role: one (t-slab, n-tile). M = 128 batches for time t, N = 128, K=2048.
// R3 lesson (FETCH 574 MB): gemm may NOT share an XCD/L2 with phase2 — its
// X/W streams evict phase2's 2 MB WT working set (the latency-critical data).
// This role now runs only on XCDs 4..7 (see role mapping in mega_kernel).
// Inner loop: double-buffered LDS, ONE barrier per k-tile; next tile's global
// loads issue right after the LDS write so their latency hides under the
// 512-FMA block. Summation order (BK=16, k ascending) identical -> Xi bitwise
// identical. Xi stores stay nontemporal (consumed on phase2 XCDs, not here).
// Race audit: a wave writes buf[cur] at tile t only after passing
// barrier(t-1), which requires all waves completed FMA(t-2) — the last
// readers of buf[cur]. Race-free.
// ---------------------------------------------------------------------------
__device__ __forceinline__ void gemm_role(int g,
    const float* __restrict__ X, const float* __restrict__ W,
    const float* __restrict__ bi2h, const float* __restrict__ bh2h,
    float* __restrict__ Xi, int* __restrict__ xi_done)
{
    __shared__ float As[2][16][132];
    __shared__ float Bs[2][16][132];
    const int t   = g >> 3;            // slab; ascending with dispatch order
    const int n0  = (g & 7) << 7;      // n-tile (128 cols of H)
    const int tid = threadIdx.x;
    const int tm8 = (tid >> 5) << 3;   // 0..120, 8 output rows (batches)
    const int tn4 = (tid & 31) << 2;   // 0..124, 4 output cols
    const int ldr = tid >> 2;          // 0..127 staging row
    const int ldc = (tid & 3) << 2;    // 0,4,8,12 staging k-offset

    const float* Xp = X + (size_t)ldr * (T_ * D_) + (size_t)t * D_ + ldc;
    const float* Wp = W + (size_t)(n0 + ldr) * D_ + ldc;

    float acc[8][4];
#pragma unroll
    for (int i = 0; i < 8; ++i)
#pragma unroll
        for (int j = 0; j < 4; ++j) acc[i][j] = 0.0f;

    float4 va = *(const float4*)(Xp);   // tile 0 staged in regs
    float4 vb = *(const float4*)(Wp);
    constexpr int NT = D_ / 16;         // 128 k-tiles
    for (int tile = 0; tile < NT; ++tile) {
        const int cur = tile & 1;
        As[cur][ldc + 0][ldr] = va.x; As[cur][ldc + 1][ldr] = va.y;
        As[cur][ldc + 2][ldr] = va.z; As[cur][ldc + 3][ldr] = va.w;
        Bs[cur][ldc + 0][ldr] = vb.x; Bs[cur][ldc + 1][ldr] = vb.y;
        Bs[cur][ldc + 2][ldr] = vb.z; Bs[cur][ldc + 3][ldr] = vb.w;
        if (tile + 1 < NT) {            // issue next tile's loads (hidden by FMAs)
            va = *(const float4*)(Xp + (tile + 1) * 16);
            vb = *(const float4*)(Wp + (tile + 1) * 16);
        }
        __syncthreads();                // buf[cur] fully written by all waves
#pragma unroll
        for (int k = 0; k < 16; ++k) {
            float4 A0 = *(const float4*)&As[cur][k][tm8];
            float4 A1 = *(const float4*)&As[cur][k][tm8 + 4];
            float4 B0 = *(const float4*)&Bs[cur][k][tn4];
            float a[8] = {A0.x, A0.y, A0.z, A0.w, A1.x, A1.y, A1.z, A1.w};
            float b4[4] = {B0.x, B0.y, B0.z, B0.w};
#pragma unroll
            for (int i = 0; i < 8; ++i)
#pragma unroll
                for (int j = 0; j < 4; ++j) acc[i][j] += a[i] * b4[j];
        }
    }

    float bs[4];
#pragma unroll
    for (int j = 0; j < 4; ++j) {
        int n = n0 + tn4 + j;
        bs[j] = bi2h[n] + bh2h[n];
    }
#pragma unroll
    for (int i = 0; i < 8; ++i) {
        size_t row = (size_t)(tm8 + i) * T_ + t;   // Xi row = b*T + t
        vfloat4 o = {acc[i][0] + bs[0], acc[i][1] + bs[1],
                     acc[i][2] + bs[2], acc[i][3] + bs[3]};
        __builtin_nontemporal_store(o, (vfloat4*)(Xi + row * H_ + n0 + tn4));
    }
    __syncthreads();   // drains vmcnt(0) in every thread -> stores visible
    if (tid == 0)
        __hip_atomic_fetch_add(&xi_done[t], 1, __ATOMIC_RELEASE,
                               __HIP_MEMORY_SCOPE_AGENT);
}

// ---------------------------------------------------------------------------
// Fused kernel, XCD-partitioned roles.
// slot = blk%8, widx = blk>>3 (round-robin dispatch => slot == XCD).
//   slot<4, widx<64  : phase2 (256 blocks, 64/XCD on XCDs 0..3 = full capacity
//                      at 2 blocks/CU; half = slot&1 so each XCD hosts ONE
//                      column-half -> 2 MB WT working set, NO gemm in these L2s)
//   slot>=4          : gemm (800 blocks stream through XCDs 4..7)
//   slot<4, widx>=64 : filler, returns immediately (placed after phase2 owns
//                      0..3; retires instantly -> no deadlock)
// Deadlock audit: all 256 phase2 blocks are in the first 512 dispatched ->
// resident from t=0 (pair partners co-resident); gemm blocks never wait;
// fillers retire instantly; slab-0 producers (blk 4..7,12..15) resident at
// launch. In-order dispatch fill => no cycle in the wait graph.
// Phase2 control flow identical to the proven 2027 µs version; only the
// pair/half derivation changed.
// ---------------------------------------------------------------------------
__global__ __launch_bounds__(512, 4) void mega_kernel(
    const float* __restrict__ X,       // [B,T,D] raw input
    const float* __restrict__ Wi2h,    // [H, D]
    const float* __restrict__ bi2h,
    const float* __restrict__ bh2h,
    float* __restrict__ Xi,            // [B*T, H] produced by gemm role
    int* __restrict__ xi_done,         // [T] slab completion counters
    const float* __restrict__ WT,      // [j*H + h]
    const float* __restrict__ W2oT,    // [h*O + o]
    const float* __restrict__ bh2o,
    const float* __restrict__ thr_h_g,
    const float* __restrict__ thr_o_g,
    const float* __restrict__ hm0,
    const float* __restrict__ hs0,
    const float* __restrict__ om0,
    unsigned long long* __restrict__ g_mask,   // [B][2 buf][2 half][8]
    int* __restrict__ g_flag,                  // [B][2 half]
    ulonglong2* __restrict__ spk,              // [B*H]
    float* __restrict__ osum_out,              // [B,O]
    float* __restrict__ nbr_acc)               // [T] pre-zeroed
{
    const int slot = blockIdx.x & 7;
    const int widx = blockIdx.x >> 3;
    if (slot >= 4) {
        int g = widx * 4 + (slot - 4);
        if (g < GEMM_NB)
            gemm_role(g, X, Wi2h, bi2h, bh2h, Xi, xi_done);
        return;
    }
    if (widx >= 64) return;             // filler

    const int pair = widx * 2 + (slot >> 1);   // 0..127 (= batch b)
    const int half = slot & 1;                 // XCD parity hosts one half
    const int b = pair;
    const int tid = threadIdx.x;
    const int lane = tid & 63;
    const int wv = tid >> 6;            // 0..7
    const int h0 = half * H2;
    const int ph0 = h0 ^ H2;
    const int h = h0 + tid;

    __shared__ int   s_list[1024];              // [0,512) own, [512,1024) partner
    __shared__ float4 s_red[4][128];
    __shared__ unsigned long long s_mask[16];   // global word order
    __shared__ float s_opart[8][O_];
    __shared__ float s_om[O_], s_osum[O_], s_tho[O_], s_bo[O_];

    float hm = hm0[(size_t)b * H_ + h];
    const float thr = thr_h_g[h];

    if (half == 0 && tid < O_) {
        s_om[tid]   = om0[b * O_ + tid];
        s_osum[tid] = 0.0f;
        s_tho[tid]  = thr_o_g[tid];
        s_bo[tid]   = bh2o[tid];
    }

    // initial mask(-1) from hs0 — both halves computed locally, no exchange
    {
        bool own = hs0[(size_t)b * H_ + h] > 0.5f;
        bool par = hs0[(size_t)b * H_ + ph0 + tid] > 0.5f;
        unsigned long long mo = __ballot(own), mp = __ballot(par);
        if (lane == 0) { s_mask[half * 8 + wv] = mo; s_mask[(half ^ 1) * 8 + wv] = mp; }
    }
    __syncthreads();

    int cnt_own;
    {   // own list (region A) — redundant per-thread prefix, no extra barrier
        const int ow = half * 8;
        int pc[8];
#pragma unroll
        for (int k = 0; k < 8; ++k) pc[k] = __popcll(s_mask[ow + k]);
        int basew = 0, tot = 0;
#pragma unroll
        for (int k = 0; k < 8; ++k) { if (k < wv) basew += pc[k]; tot += pc[k]; }
        cnt_own = tot;
        unsigned long long mw = s_mask[ow + wv];
        if ((mw >> lane) & 1ull)
            s_list[basew + __popcll(mw & ((1ull << lane) - 1ull))] = h;
    }
    // wait for the first Xi slab before entering the loop (acquire precedes
    // every thread's t=0 Xi load via the barrier below)
    if (tid == 0) {
        while (__hip_atomic_load(&xi_done[0], __ATOMIC_ACQUIRE,
                                 __HIP_MEMORY_SCOPE_AGENT) < XI_READY)
            __builtin_amdgcn_s_sleep(1);
    }
    __syncthreads();

    const float4* __restrict__ wt4b = (const float4*)WT + (h0 >> 2); // + j*256 + cid
    const int g = tid >> 7;          // list group 0..3
    const int cid = tid & 127;       // float4 column within half
    const int fl_partner = pair * 2 + (half ^ 1);
    const int fl_self    = pair * 2 + half;
    unsigned long long bits0 = 0, bits1 = 0;

    for (int t = 0; t <= T_; ++t) {
        const bool full = (t < T_);
        float xi = 0.0f;
        if (full) xi = Xi[((size_t)b * T_ + t) * H_ + h];

        float4 c0 = {0,0,0,0}, c1 = {0,0,0,0}, c2 = {0,0,0,0}, c3 = {0,0,0,0};
        float4 c4 = {0,0,0,0}, c5 = {0,0,0,0}, c6 = {0,0,0,0}, c7 = {0,0,0,0};

        // ---- phase 1: own-half active rows (no partner dependency) ----
        if (full) {
            const int c = cnt_own;
            int l = g;
            for (; l + 28 < c; l += 32) {
                int j0 = s_list[l],      j1 = s_list[l + 4];
                int j2 = s_list[l + 8],  j3 = s_list[l + 12];
                int j4 = s_list[l + 16], j5 = s_list[l + 20];
                int j6 = s_list[l + 24], j7 = s_list[l + 28];
                f4acc(c0, wt4b[(size_t)j0 * 256 + cid]);
                f4acc(c1, wt4b[(size_t)j1 * 256 + cid]);
                f4acc(c2, wt4b[(size_t)j2 * 256 + cid]);
                f4acc(c3, wt4b[(size_t)j3 * 256 + cid]);
                f4acc(c4, wt4b[(size_t)j4 * 256 + cid]);
                f4acc(c5, wt4b[(size_t)j5 * 256 + cid]);
                f4acc(c6, wt4b[(size_t)j6 * 256 + cid]);
                f4acc(c7, wt4b[(size_t)j7 * 256 + cid]);
            }
            for (; l < c; l += 4) f4acc(c0, wt4b[(size_t)s_list[l] * 256 + cid]);
        }

        // ---- spin for partner mask(t-1) + next Xi slab — latency hidden by
        //      phase 1; acquire happens-before next iteration's Xi loads ----
        if (tid == 0) {
            if (t > 0) {
                while (__hip_atomic_load(&g_flag[fl_partner], __ATOMIC_ACQUIRE,
                                         __HIP_MEMORY_SCOPE_AGENT) < t)
                    __builtin_amdgcn_s_sleep(1);
            }
            if (t + 1 < T_) {
                while (__hip_atomic_load(&xi_done[t + 1], __ATOMIC_ACQUIRE,
                                         __HIP_MEMORY_SCOPE_AGENT) < XI_READY)
                    __builtin_amdgcn_s_sleep(1);
            }
        }
        __syncthreads();                            // B1
        if (t > 0 && tid < 8) {
            const unsigned long long* pm =
                g_mask + (((size_t)(pair * 2 + ((t - 1) & 1)) * 2 + (half ^ 1)) * 8);
            s_mask[(half ^ 1) * 8 + tid] =
                __hip_atomic_load(&pm[tid], __ATOMIC_RELAXED, __HIP_MEMORY_SCOPE_AGENT);
        }
        __syncthreads();                            // B2

        int cnt_p;
        {   // partner list (region B) — redundant prefix
            const int pw = (half ^ 1) * 8;
            int pc[8];
#pragma unroll
            for (int k = 0; k < 8; ++k) pc[k] = __popcll(s_mask[pw + k]);
            int basew = 0, tot = 0;
#pragma unroll
            for (int k = 0; k < 8; ++k) { if (k < wv) basew += pc[k]; tot += pc[k]; }
            cnt_p = tot;
            unsigned long long mw = s_mask[pw + wv];
            if ((mw >> lane) & 1ull)
                s_list[512 + basew + __popcll(mw & ((1ull << lane) - 1ull))] =
                    ph0 + wv * 64 + lane;
        }
        __syncthreads();                            // B3

        // ---- phase 2: partner-half active rows ----
        if (full) {
            const int c = cnt_p;
            int l = g;
            for (; l + 28 < c; l += 32) {
                int j0 = s_list[512 + l],      j1 = s_list[512 + l + 4];
                int j2 = s_list[512 + l + 8],  j3 = s_list[512 + l + 12];
                int j4 = s_list[512 + l + 16], j5 = s_list[512 + l + 20];
                int j6 = s_list[512 + l + 24], j7 = s_list[512 + l + 28];
                f4acc(c0, wt4b[(size_t)j0 * 256 + cid]);
                f4acc(c1, wt4b[(size_t)j1 * 256 + cid]);
                f4acc(c2, wt4b[(size_t)j2 * 256 + cid]);
                f4acc(c3, wt4b[(size_t)j3 * 256 + cid]);
                f4acc(c4, wt4b[(size_t)j4 * 256 + cid]);
                f4acc(c5, wt4b[(size_t)j5 * 256 + cid]);
                f4acc(c6, wt4b[(size_t)j6 * 256 + cid]);
                f4acc(c7, wt4b[(size_t)j7 * 256 + cid]);
            }
            for (; l < c; l += 4) f4acc(c0, wt4b[(size_t)s_list[512 + l] * 256 + cid]);
        }

        // ---- o-layer partials for step t-1 (half0 only; L2 W2oT reads) ----
        if (half == 0 && t > 0 && lane < O_) {
            float op = 0.0f;
            for (int q = wv; q < cnt_own; q += 8) op += W2oT[s_list[q] * O_ + lane];
            for (int q = wv; q < cnt_p; q += 8)  op += W2oT[s_list[512 + q] * O_ + lane];
            s_opart[wv][lane] = op;
        }

        {   // combine chains -> s_red
            f4acc(c0, c1); f4acc(c2, c3); f4acc(c4, c5); f4acc(c6, c7);
            f4acc(c0, c2); f4acc(c4, c6); f4acc(c0, c4);
            s_red[g][cid] = c0;
        }
        const int hidprev = cnt_own + cnt_p;        // popcount of mask(t-1)
        __syncthreads();                            // B4

        if (full) {
            const float* rf = (const float*)s_red;
            float val = rf[tid] + rf[512 + tid] + rf[1024 + tid] + rf[1536 + tid];
            hm += xi + val;
            bool sp = (hm - thr) > 0.0f;
            if (sp) hm = 0.0f;
            if (hm < -thr) hm = -thr;
            if (sp) { if (t < 64) bits0 |= 1ull << t; else bits1 |= 1ull << (t - 64); }
            unsigned long long m = __ballot(sp);
            if (lane == 0) {
                s_mask[half * 8 + wv] = m;
                unsigned long long* gm =
                    g_mask + (((size_t)(pair * 2 + (t & 1)) * 2 + half) * 8);
                __hip_atomic_store(&gm[wv], m, __ATOMIC_RELAXED,
                                   __HIP_MEMORY_SCOPE_AGENT);
            }
        }

        // ---- o-LIF(t-1) + nbr(t-1): half0 ----
        if (half == 0 && t > 0) {
            float osp_l = 0.0f;
            if (tid < O_) {
                float oin = s_bo[tid];
#pragma unroll
                for (int w = 0; w < 8; ++w) oin += s_opart[w][tid];
                float om = s_om[tid] + oin;
                float osp = ((om - s_tho[tid]) > 0.0f) ? 1.0f : 0.0f;
                if (osp > 0.5f) om = 0.0f;
                if (om < -s_tho[tid]) om = -s_tho[tid];
                s_om[tid] = om;
                s_osum[tid] += osp;
                osp_l = osp;
            }
            if (wv == 0) {
                float cc = osp_l;
                cc += __shfl_xor(cc, 1);  cc += __shfl_xor(cc, 2);
                cc += __shfl_xor(cc, 4);  cc += __shfl_xor(cc, 8);
                cc += __shfl_xor(cc, 16); cc += __shfl_xor(cc, 32);
                if (lane == 0)
                    atomicAdd(&nbr_acc[t - 1], cc + (float)hidprev); // exact ints
            }
        }
        __syncthreads();                            // B5
        if (full && tid == 0)
            __hip_atomic_store(&g_flag[fl_self], t + 1, __ATOMIC_RELEASE,
                               __HIP_MEMORY_SCOPE_AGENT);
        if (full) {   // rebuild own list (region A) for next iteration
            const int ow = half * 8;
            int pc[8];
#pragma unroll
            for (int k = 0; k < 8; ++k) pc[k] = __popcll(s_mask[ow + k]);
            int basew = 0, tot = 0;
#pragma unroll
            for (int k = 0; k < 8; ++k) { if (k < wv) basew += pc[k]; tot += pc[k]; }
            cnt_own = tot;
            unsigned long long mw = s_mask[ow + wv];
            if ((mw >> lane) & 1ull)
                s_list[basew + __popcll(mw & ((1ull << lane) - 1ull))] = h;
        }
        __syncthreads();                            // B6
    }

    ulonglong2 vv; vv.x = bits0; vv.y = bits1;
    spk[(size_t)b * H_ + h] = vv;
    if (half == 0 && tid < O_) osum_out[b * O_ + tid] = s_osum[tid];
}

// ---------------------------------------------------------------------------
// sliding-window mean of spike bitmasks
// ---------------------------------------------------------------------------
__global__ __launch_bounds__(256) void filt_kernel(const ulonglong2* __restrict__ spk,
                                                   float* __restrict__ outf)
{
    int i = blockIdx.x * 256 + threadIdx.x;
    ulonglong2 v = spk[i];
    float* o = outf + (size_t)i * 91;
    int s = __popcll(v.x & 0x3FFull);
    o[0] = (float)s * 0.1f;
#pragma unroll 1
    for (int tau = 1; tau <= 90; ++tau) {
        int ta = tau + 9, tsb = tau - 1;
        int add = (ta < 64) ? (int)((v.x >> ta) & 1ull) : (int)((v.y >> (ta - 64)) & 1ull);
        int sub = (tsb < 64) ? (int)((v.x >> tsb) & 1ull) : (int)((v.y >> (tsb - 64)) & 1ull);
        s += add - sub;
        o[tau] = (float)s * 0.1f;
    }
}

// ---------------------------------------------------------------------------
// predictions / loss / nbr scaling
// ---------------------------------------------------------------------------
__global__ __launch_bounds__(256) void final_kernel(const float* __restrict__ osum,
                                                    const int* __restrict__ labels,
                                                    float* __restrict__ dout)
{
    __shared__ float s_loss[B_];
    int tid = threadIdx.x;
    if (tid < B_) {
        int b = tid;
        float v[O_];
#pragma unroll
        for (int o = 0; o < O_; ++o) v[o] = osum[b * O_ + o];
        float mv = v[0];
        int am = 0;
#pragma unroll
        for (int o = 1; o < O_; ++o)
            if (v[o] > mv) { mv = v[o]; am = o; }   // strict >: first max wins
        float se = 0.0f;
#pragma unroll
        for (int o = 0; o < O_; ++o) se += expf(v[o] - mv);
        float lse = mv + logf(se);
        dout[b] = (float)am;
        s_loss[b] = v[labels[b]] - lse;
    }
    if (tid >= 128 && tid < 128 + T_) {
        dout[129 + (tid - 128)] *= (1.0f / (float)B_);
    }
    __syncthreads();
    if (tid == 0) {
        float s = 0.0f;
        for (int b = 0; b < B_; ++b) s += s_loss[b];
        dout[128] = -s / (float)B_;
    }
}

// ---------------------------------------------------------------------------
extern "C" void kernel_launch(void* const* d_in, const int* in_sizes, int n_in,
                              void* d_out, int out_size, void* d_ws, size_t ws_size,
                              hipStream_t stream)
{
    const float* input  = (const float*)d_in[0];
    const int*   labels = (const int*)d_in[1];
    const float* hm0    = (const float*)d_in[2];
    const float* hs0    = (const float*)d_in[3];
    const float* om0    = (const float*)d_in[4];
    const float* Wi2h   = (const float*)d_in[6];
    const float* bi2h   = (const float*)d_in[7];
    const float* Wh2h   = (const float*)d_in[8];
    const float* bh2h   = (const float*)d_in[9];
    const float* Wh2o   = (const float*)d_in[10];
    const float* bh2o   = (const float*)d_in[11];
    const float* thr_h  = (const float*)d_in[12];
    const float* thr_o  = (const float*)d_in[13];

    float* out  = (float*)d_out;
    float* nbr  = out + 129;
    float* filt = out + 229;

    char* ws = (char*)d_ws;
    float*      Xi     = (float*)(ws);                   // 52,428,800
    float*      WT     = (float*)(ws + 52428800);        //  4,194,304
    float*      W2oT   = (float*)(ws + 56623104);        //     81,920
    ulonglong2* spk    = (ulonglong2*)(ws + 56705024);   //  2,097,152
    float*      osum   = (float*)(ws + 58802176);        //     10,240
    unsigned long long* g_mask = (unsigned long long*)(ws + 58812416); // 32,768
    int*        g_flag  = (int*)(ws + 58845184);         //      1,024
    int*        xi_done = (int*)(ws + 58846208);         //        400

    prep_kernel<<<80, 256, 0, stream>>>(Wh2o, W2oT, nbr, g_flag, xi_done);
    transpose_kernel<<<dim3(32, 32), dim3(32, 8), 0, stream>>>(Wh2h, WT);
    mega_kernel<<<GRID_NB, 512, 0, stream>>>(
        input, Wi2h, bi2h, bh2h, Xi, xi_done,
        WT, W2oT, bh2o, thr_h, thr_o, hm0, hs0, om0,
        g_mask, g_flag, spk, osum, nbr);
    filt_kernel<<<512, 256, 0, stream>>>(spk, filt);
    final_kernel<<<1, 256, 0, stream>>>(osum, labels, out);
}

// Round 6
// 2008.066 us; speedup vs baseline: 1.5397x; 1.5397x over previous
//
#include <hip/hip_runtime.h>
#include <hip/hip_bf16.h>
#include <cstdint>
#include <cstddef>

#define B_ 128
#define T_ 100
#define D_ 2048
#define H_ 1024
#define O_ 20
#define H2 512

__device__ inline void f4acc(float4& a, const float4 v) {
    a.x += v.x; a.y += v.y; a.z += v.z; a.w += v.w;
}

// ---------------------------------------------------------------------------
// prep: W2oT[h][o] = Wh2o[o][h]; zero nbr accumulators and pair flags.
// ---------------------------------------------------------------------------
__global__ __launch_bounds__(256) void prep_kernel(const float* __restrict__ Wh2o,
                                                   float* __restrict__ W2oT,
                                                   float* __restrict__ nbr,
                                                   int* __restrict__ g_flag)
{
    int i = blockIdx.x * 256 + threadIdx.x;
    if (i < H_ * O_) {
        int hh = i / O_;
        int oo = i - hh * O_;
        W2oT[i] = Wh2o[oo * H_ + hh];
    }
    if (i < T_) nbr[i] = 0.0f;
    if (i < B_ * 2) g_flag[i] = 0;
}

// ---------------------------------------------------------------------------
// transpose Wh2h[h][j] -> WT[j][h]
// ---------------------------------------------------------------------------
__global__ __launch_bounds__(256) void transpose_kernel(const float* __restrict__ A,
                                                        float* __restrict__ AT)
{
    __shared__ float tile[32][33];
    int bx = blockIdx.x * 32, by = blockIdx.y * 32;
    int tx = threadIdx.x, ty = threadIdx.y;  // block (32,8)
#pragma unroll
    for (int i = 0; i < 32; i += 8)
        tile[ty + i][tx] = A[(size_t)(by + ty + i) * H_ + bx + tx];
    __syncthreads();
#pragma unroll
    for (int i = 0; i < 32; i += 8)
        AT[(size_t)(bx + ty + i) * H_ + by + tx] = tile[tx][ty + i];
}

// ---------------------------------------------------------------------------
// Xi = X @ Wi2h^T + (bi2h + bh2h).  128x128x16 tile, 256 threads, 8x8 micro.
// R6 change vs the 2027 µs baseline: double-buffered LDS, ONE barrier per
// k-tile (was 2), and the next tile's global loads are register-staged before
// the barrier so their L2/HBM latency hides under the 1024-FMA block.
// Race audit: a wave writes buf[cur] at tile t only after passing
// barrier(t-1); every wave's FMA(t-2) — the last reads of buf[cur] — precede
// barrier(t-1) in program order. Race-free. FMA/summation order is UNCHANGED
// (BK=16, k ascending) -> Xi bitwise identical -> phase2 identical.
// ---------------------------------------------------------------------------
__global__ __launch_bounds__(256) void gemm_xi_kernel(
    const float* __restrict__ X,     // [B*T, D]
    const float* __restrict__ W,     // [H, D]
    const float* __restrict__ bi2h,
    const float* __restrict__ bh2h,
    float* __restrict__ Xi)          // [B*T, H]
{
    constexpr int BM = 128, BN = 128, BK = 16;
    __shared__ float As[2][BK][BM + 4];
    __shared__ float Bs[2][BK][BN + 4];
    const int tid = threadIdx.x;
    const int m0 = blockIdx.x * BM;
    const int n0 = blockIdx.y * BN;
    const int wave = tid >> 6;
    const int lane = tid & 63;
    const int tm = ((wave >> 1) << 3) | (lane >> 3);   // 0..15
    const int tn = ((wave & 1) << 3) | (lane & 7);     // 0..15
    const int ldr = tid >> 2;          // 0..63
    const int ldc = (tid & 3) << 2;    // 0,4,8,12

    float acc[8][8];
#pragma unroll
    for (int i = 0; i < 8; ++i)
#pragma unroll
        for (int j = 0; j < 8; ++j) acc[i][j] = 0.0f;

    const float* Xp0 = X + (size_t)(m0 + ldr) * D_ + ldc;
    const float* Xp1 = X + (size_t)(m0 + ldr + 64) * D_ + ldc;
    const float* Wp0 = W + (size_t)(n0 + ldr) * D_ + ldc;
    const float* Wp1 = W + (size_t)(n0 + ldr + 64) * D_ + ldc;

    // stage tile 0
    float4 xa0 = *(const float4*)(Xp0);
    float4 xa1 = *(const float4*)(Xp1);
    float4 wb0 = *(const float4*)(Wp0);
    float4 wb1 = *(const float4*)(Wp1);

    constexpr int NT = D_ / BK;        // 128 k-tiles
    for (int tile = 0; tile < NT; ++tile) {
        const int cur = tile & 1;
        As[cur][ldc + 0][ldr]      = xa0.x; As[cur][ldc + 1][ldr]      = xa0.y;
        As[cur][ldc + 2][ldr]      = xa0.z; As[cur][ldc + 3][ldr]      = xa0.w;
        As[cur][ldc + 0][ldr + 64] = xa1.x; As[cur][ldc + 1][ldr + 64] = xa1.y;
        As[cur][ldc + 2][ldr + 64] = xa1.z; As[cur][ldc + 3][ldr + 64] = xa1.w;
        Bs[cur][ldc + 0][ldr]      = wb0.x; Bs[cur][ldc + 1][ldr]      = wb0.y;
        Bs[cur][ldc + 2][ldr]      = wb0.z; Bs[cur][ldc + 3][ldr]      = wb0.w;
        Bs[cur][ldc + 0][ldr + 64] = wb1.x; Bs[cur][ldc + 1][ldr + 64] = wb1.y;
        Bs[cur][ldc + 2][ldr + 64] = wb1.z; Bs[cur][ldc + 3][ldr + 64] = wb1.w;
        if (tile + 1 < NT) {           // prefetch next tile (hidden by FMAs)
            const int ko = (tile + 1) * BK;
            xa0 = *(const float4*)(Xp0 + ko);
            xa1 = *(const float4*)(Xp1 + ko);
            wb0 = *(const float4*)(Wp0 + ko);
            wb1 = *(const float4*)(Wp1 + ko);
        }
        __syncthreads();               // buf[cur] fully written by all waves
#pragma unroll
        for (int k = 0; k < BK; ++k) {
            float4 A0 = *(const float4*)&As[cur][k][tm * 8];
            float4 A1 = *(const float4*)&As[cur][k][tm * 8 + 4];
            float4 B0 = *(const float4*)&Bs[cur][k][tn * 8];
            float4 B1 = *(const float4*)&Bs[cur][k][tn * 8 + 4];
            float a[8] = {A0.x, A0.y, A0.z, A0.w, A1.x, A1.y, A1.z, A1.w};
            float bb[8] = {B0.x, B0.y, B0.z, B0.w, B1.x, B1.y, B1.z, B1.w};
#pragma unroll
            for (int i = 0; i < 8; ++i)
#pragma unroll
                for (int j = 0; j < 8; ++j) acc[i][j] += a[i] * bb[j];
        }
    }

    float bsum[8];
#pragma unroll
    for (int j = 0; j < 8; ++j) {
        int n = n0 + tn * 8 + j;
        bsum[j] = bi2h[n] + bh2h[n];
    }
#pragma unroll
    for (int i = 0; i < 8; ++i) {
        size_t row = (size_t)(m0 + tm * 8 + i);
        float4 o0 = {acc[i][0] + bsum[0], acc[i][1] + bsum[1],
                     acc[i][2] + bsum[2], acc[i][3] + bsum[3]};
        float4 o1 = {acc[i][4] + bsum[4], acc[i][5] + bsum[5],
                     acc[i][6] + bsum[6], acc[i][7] + bsum[7]};
        *(float4*)(Xi + row * H_ + n0 + tn * 8)     = o0;
        *(float4*)(Xi + row * H_ + n0 + tn * 8 + 4) = o1;
    }
}

// ---------------------------------------------------------------------------
// phase2 — IDENTICAL to the proven 2027 µs version (R3's overlapped control
// flow + R2's XCD placement). pair = blk>>1, half = blk&1 => XCD k hosts ONLY
// column-half k&1 (2 MB WT working set per XCD). Per step: gather own-half
// active rows first (hides partner publish latency), spin for partner
// mask(t-1), gather partner rows. o-layer one step behind on half 0.
// ---------------------------------------------------------------------------
__global__ __launch_bounds__(512) void phase2_kernel(
    const float* __restrict__ Xi,      // [B*T, H]
    const float* __restrict__ WT,      // [j*H + h]
    const float* __restrict__ W2oT,    // [h*O + o]
    const float* __restrict__ bh2o,
    const float* __restrict__ thr_h_g,
    const float* __restrict__ thr_o_g,
    const float* __restrict__ hm0,
    const float* __restrict__ hs0,
    const float* __restrict__ om0,
    unsigned long long* __restrict__ g_mask,   // [B][2 buf][2 half][8]
    int* __restrict__ g_flag,                  // [B][2 half]
    ulonglong2* __restrict__ spk,              // [B*H]
    float* __restrict__ osum_out,              // [B,O]
    float* __restrict__ nbr_acc)               // [T] pre-zeroed
{
    const int pair = blockIdx.x >> 1;   // R2 placement: adjacent blocks pair up
    const int half = blockIdx.x & 1;    // XCD k hosts only half k&1
    const int b = pair;
    const int tid = threadIdx.x;
    const int lane = tid & 63;
    const int wv = tid >> 6;            // 0..7
    const int h0 = half * H2;
    const int ph0 = h0 ^ H2;
    const int h = h0 + tid;

    __shared__ int   s_list[1024];              // [0,512) own, [512,1024) partner
    __shared__ float4 s_red[4][128];
    __shared__ unsigned long long s_mask[16];   // global word order
    __shared__ float s_opart[8][O_];
    __shared__ float s_om[O_], s_osum[O_], s_tho[O_], s_bo[O_];

    float hm = hm0[(size_t)b * H_ + h];
    const float thr = thr_h_g[h];

    if (half == 0 && tid < O_) {
        s_om[tid]   = om0[b * O_ + tid];
        s_osum[tid] = 0.0f;
        s_tho[tid]  = thr_o_g[tid];
        s_bo[tid]   = bh2o[tid];
    }

    // initial mask(-1) from hs0 — both halves computed locally, no exchange
    {
        bool own = hs0[(size_t)b * H_ + h] > 0.5f;
        bool par = hs0[(size_t)b * H_ + ph0 + tid] > 0.5f;
        unsigned long long mo = __ballot(own), mp = __ballot(par);
        if (lane == 0) { s_mask[half * 8 + wv] = mo; s_mask[(half ^ 1) * 8 + wv] = mp; }
    }
    __syncthreads();

    int cnt_own;
    {   // own list (region A) — redundant per-thread prefix, no extra barrier
        const int ow = half * 8;
        int pc[8];
#pragma unroll
        for (int k = 0; k < 8; ++k) pc[k] = __popcll(s_mask[ow + k]);
        int basew = 0, tot = 0;
#pragma unroll
        for (int k = 0; k < 8; ++k) { if (k < wv) basew += pc[k]; tot += pc[k]; }
        cnt_own = tot;
        unsigned long long mw = s_mask[ow + wv];
        if ((mw >> lane) & 1ull)
            s_list[basew + __popcll(mw & ((1ull << lane) - 1ull))] = h;
    }
    __syncthreads();

    const float4* __restrict__ wt4b = (const float4*)WT + (h0 >> 2); // + j*256 + cid
    const int g = tid >> 7;          // list group 0..3
    const int cid = tid & 127;       // float4 column within half
    const int fl_partner = pair * 2 + (half ^ 1);
    const int fl_self    = pair * 2 + half;
    unsigned long long bits0 = 0, bits1 = 0;

    for (int t = 0; t <= T_; ++t) {
        const bool full = (t < T_);
        float xi = 0.0f;
        if (full) xi = Xi[((size_t)b * T_ + t) * H_ + h];

        float4 c0 = {0,0,0,0}, c1 = {0,0,0,0}, c2 = {0,0,0,0}, c3 = {0,0,0,0};
        float4 c4 = {0,0,0,0}, c5 = {0,0,0,0}, c6 = {0,0,0,0}, c7 = {0,0,0,0};

        // ---- phase 1: own-half active rows (no partner dependency) ----
        if (full) {
            const int c = cnt_own;
            int l = g;
            for (; l + 28 < c; l += 32) {
                int j0 = s_list[l],      j1 = s_list[l + 4];
                int j2 = s_list[l + 8],  j3 = s_list[l + 12];
                int j4 = s_list[l + 16], j5 = s_list[l + 20];
                int j6 = s_list[l + 24], j7 = s_list[l + 28];
                f4acc(c0, wt4b[(size_t)j0 * 256 + cid]);
                f4acc(c1, wt4b[(size_t)j1 * 256 + cid]);
                f4acc(c2, wt4b[(size_t)j2 * 256 + cid]);
                f4acc(c3, wt4b[(size_t)j3 * 256 + cid]);
                f4acc(c4, wt4b[(size_t)j4 * 256 + cid]);
                f4acc(c5, wt4b[(size_t)j5 * 256 + cid]);
                f4acc(c6, wt4b[(size_t)j6 * 256 + cid]);
                f4acc(c7, wt4b[(size_t)j7 * 256 + cid]);
            }
            for (; l < c; l += 4) f4acc(c0, wt4b[(size_t)s_list[l] * 256 + cid]);
        }

        // ---- spin for partner mask(t-1) — latency hidden by phase 1 ----
        if (t > 0 && tid == 0) {
            while (__hip_atomic_load(&g_flag[fl_partner], __ATOMIC_ACQUIRE,
                                     __HIP_MEMORY_SCOPE_AGENT) < t)
                __builtin_amdgcn_s_sleep(1);
        }
        __syncthreads();                            // B1
        if (t > 0 && tid < 8) {
            const unsigned long long* pm =
                g_mask + (((size_t)(pair * 2 + ((t - 1) & 1)) * 2 + (half ^ 1)) * 8);
            s_mask[(half ^ 1) * 8 + tid] =
                __hip_atomic_load(&pm[tid], __ATOMIC_RELAXED, __HIP_MEMORY_SCOPE_AGENT);
        }
        __syncthreads();                            // B2

        int cnt_p;
        {   // partner list (region B) — redundant prefix
            const int pw = (half ^ 1) * 8;
            int pc[8];
#pragma unroll
            for (int k = 0; k < 8; ++k) pc[k] = __popcll(s_mask[pw + k]);
            int basew = 0, tot = 0;
#pragma unroll
            for (int k = 0; k < 8; ++k) { if (k < wv) basew += pc[k]; tot += pc[k]; }
            cnt_p = tot;
            unsigned long long mw = s_mask[pw + wv];
            if ((mw >> lane) & 1ull)
                s_list[512 + basew + __popcll(mw & ((1ull << lane) - 1ull))] =
                    ph0 + wv * 64 + lane;
        }
        __syncthreads();                            // B3

        // ---- phase 2: partner-half active rows ----
        if (full) {
            const int c = cnt_p;
            int l = g;
            for (; l + 28 < c; l += 32) {
                int j0 = s_list[512 + l],      j1 = s_list[512 + l + 4];
                int j2 = s_list[512 + l + 8],  j3 = s_list[512 + l + 12];
                int j4 = s_list[512 + l + 16], j5 = s_list[512 + l + 20];
                int j6 = s_list[512 + l + 24], j7 = s_list[512 + l + 28];
                f4acc(c0, wt4b[(size_t)j0 * 256 + cid]);
                f4acc(c1, wt4b[(size_t)j1 * 256 + cid]);
                f4acc(c2, wt4b[(size_t)j2 * 256 + cid]);
                f4acc(c3, wt4b[(size_t)j3 * 256 + cid]);
                f4acc(c4, wt4b[(size_t)j4 * 256 + cid]);
                f4acc(c5, wt4b[(size_t)j5 * 256 + cid]);
                f4acc(c6, wt4b[(size_t)j6 * 256 + cid]);
                f4acc(c7, wt4b[(size_t)j7 * 256 + cid]);
            }
            for (; l < c; l += 4) f4acc(c0, wt4b[(size_t)s_list[512 + l] * 256 + cid]);
        }

        // ---- o-layer partials for step t-1 (half0 only; L2 W2oT reads) ----
        if (half == 0 && t > 0 && lane < O_) {
            float op = 0.0f;
            for (int q = wv; q < cnt_own; q += 8) op += W2oT[s_list[q] * O_ + lane];
            for (int q = wv; q < cnt_p; q += 8)  op += W2oT[s_list[512 + q] * O_ + lane];
            s_opart[wv][lane] = op;
        }

        {   // combine chains -> s_red
            f4acc(c0, c1); f4acc(c2, c3); f4acc(c4, c5); f4acc(c6, c7);
            f4acc(c0, c2); f4acc(c4, c6); f4acc(c0, c4);
            s_red[g][cid] = c0;
        }
        const int hidprev = cnt_own + cnt_p;        // popcount of mask(t-1)
        __syncthreads();                            // B4

        if (full) {
            const float* rf = (const float*)s_red;
            float val = rf[tid] + rf[512 + tid] + rf[1024 + tid] + rf[1536 + tid];
            hm += xi + val;
            bool sp = (hm - thr) > 0.0f;
            if (sp) hm = 0.0f;
            if (hm < -thr) hm = -thr;
            if (sp) { if (t < 64) bits0 |= 1ull << t; else bits1 |= 1ull << (t - 64); }
            unsigned long long m = __ballot(sp);
            if (lane == 0) {
                s_mask[half * 8 + wv] = m;
                unsigned long long* gm =
                    g_mask + (((size_t)(pair * 2 + (t & 1)) * 2 + half) * 8);
                __hip_atomic_store(&gm[wv], m, __ATOMIC_RELAXED,
                                   __HIP_MEMORY_SCOPE_AGENT);
            }
        }

        // ---- o-LIF(t-1) + nbr(t-1): half0 ----
        if (half == 0 && t > 0) {
            float osp_l = 0.0f;
            if (tid < O_) {
                float oin = s_bo[tid];
#pragma unroll
                for (int w = 0; w < 8; ++w) oin += s_opart[w][tid];
                float om = s_om[tid] + oin;
                float osp = ((om - s_tho[tid]) > 0.0f) ? 1.0f : 0.0f;
                if (osp > 0.5f) om = 0.0f;
                if (om < -s_tho[tid]) om = -s_tho[tid];
                s_om[tid] = om;
                s_osum[tid] += osp;
                osp_l = osp;
            }
            if (wv == 0) {
                float cc = osp_l;
                cc += __shfl_xor(cc, 1);  cc += __shfl_xor(cc, 2);
                cc += __shfl_xor(cc, 4);  cc += __shfl_xor(cc, 8);
                cc += __shfl_xor(cc, 16); cc += __shfl_xor(cc, 32);
                if (lane == 0)
                    atomicAdd(&nbr_acc[t - 1], cc + (float)hidprev); // exact ints
            }
        }
        __syncthreads();                            // B5
        if (full && tid == 0)
            __hip_atomic_store(&g_flag[fl_self], t + 1, __ATOMIC_RELEASE,
                               __HIP_MEMORY_SCOPE_AGENT);
        if (full) {   // rebuild own list (region A) for next iteration
            const int ow = half * 8;
            int pc[8];
#pragma unroll
            for (int k = 0; k < 8; ++k) pc[k] = __popcll(s_mask[ow + k]);
            int basew = 0, tot = 0;
#pragma unroll
            for (int k = 0; k < 8; ++k) { if (k < wv) basew += pc[k]; tot += pc[k]; }
            cnt_own = tot;
            unsigned long long mw = s_mask[ow + wv];
            if ((mw >> lane) & 1ull)
                s_list[basew + __popcll(mw & ((1ull << lane) - 1ull))] = h;
        }
        __syncthreads();                            // B6
    }

    ulonglong2 vv; vv.x = bits0; vv.y = bits1;
    spk[(size_t)b * H_ + h] = vv;
    if (half == 0 && tid < O_) osum_out[b * O_ + tid] = s_osum[tid];
}

// ---------------------------------------------------------------------------
// sliding-window mean of spike bitmasks
// ---------------------------------------------------------------------------
__global__ __launch_bounds__(256) void filt_kernel(const ulonglong2* __restrict__ spk,
                                                   float* __restrict__ outf)
{
    int i = blockIdx.x * 256 + threadIdx.x;
    ulonglong2 v = spk[i];
    float* o = outf + (size_t)i * 91;
    int s = __popcll(v.x & 0x3FFull);
    o[0] = (float)s * 0.1f;
#pragma unroll 1
    for (int tau = 1; tau <= 90; ++tau) {
        int ta = tau + 9, tsb = tau - 1;
        int add = (ta < 64) ? (int)((v.x >> ta) & 1ull) : (int)((v.y >> (ta - 64)) & 1ull);
        int sub = (tsb < 64) ? (int)((v.x >> tsb) & 1ull) : (int)((v.y >> (tsb - 64)) & 1ull);
        s += add - sub;
        o[tau] = (float)s * 0.1f;
    }
}

// ---------------------------------------------------------------------------
// predictions / loss / nbr scaling
// ---------------------------------------------------------------------------
__global__ __launch_bounds__(256) void final_kernel(const float* __restrict__ osum,
                                                    const int* __restrict__ labels,
                                                    float* __restrict__ dout)
{
    __shared__ float s_loss[B_];
    int tid = threadIdx.x;
    if (tid < B_) {
        int b = tid;
        float v[O_];
#pragma unroll
        for (int o = 0; o < O_; ++o) v[o] = osum[b * O_ + o];
        float mv = v[0];
        int am = 0;
#pragma unroll
        for (int o = 1; o < O_; ++o)
            if (v[o] > mv) { mv = v[o]; am = o; }   // strict >: first max wins
        float se = 0.0f;
#pragma unroll
        for (int o = 0; o < O_; ++o) se += expf(v[o] - mv);
        float lse = mv + logf(se);
        dout[b] = (float)am;
        s_loss[b] = v[labels[b]] - lse;
    }
    if (tid >= 128 && tid < 128 + T_) {
        dout[129 + (tid - 128)] *= (1.0f / (float)B_);
    }
    __syncthreads();
    if (tid == 0) {
        float s = 0.0f;
        for (int b = 0; b < B_; ++b) s += s_loss[b];
        dout[128] = -s / (float)B_;
    }
}

// ---------------------------------------------------------------------------
extern "C" void kernel_launch(void* const* d_in, const int* in_sizes, int n_in,
                              void* d_out, int out_size, void* d_ws, size_t ws_size,
                              hipStream_t stream)
{
    const float* input  = (const float*)d_in[0];
    const int*   labels = (const int*)d_in[1];
    const float* hm0    = (const float*)d_in[2];
    const float* hs0    = (const float*)d_in[3];
    const float* om0    = (const float*)d_in[4];
    const float* Wi2h   = (const float*)d_in[6];
    const float* bi2h   = (const float*)d_in[7];
    const float* Wh2h   = (const float*)d_in[8];
    const float* bh2h   = (const float*)d_in[9];
    const float* Wh2o   = (const float*)d_in[10];
    const float* bh2o   = (const float*)d_in[11];
    const float* thr_h  = (const float*)d_in[12];
    const float* thr_o  = (const float*)d_in[13];

    float* out  = (float*)d_out;
    float* nbr  = out + 129;
    float* filt = out + 229;

    char* ws = (char*)d_ws;
    float*      Xi     = (float*)(ws);                   // 52,428,800
    float*      WT     = (float*)(ws + 52428800);        //  4,194,304
    float*      W2oT   = (float*)(ws + 56623104);        //     81,920
    ulonglong2* spk    = (ulonglong2*)(ws + 56705024);   //  2,097,152
    float*      osum   = (float*)(ws + 58802176);        //     10,240
    unsigned long long* g_mask = (unsigned long long*)(ws + 58812416); // 32,768
    int*        g_flag  = (int*)(ws + 58845184);         //      1,024

    prep_kernel<<<80, 256, 0, stream>>>(Wh2o, W2oT, nbr, g_flag);
    transpose_kernel<<<dim3(32, 32), dim3(32, 8), 0, stream>>>(Wh2h, WT);
    gemm_xi_kernel<<<dim3(100, 8), 256, 0, stream>>>(input, Wi2h, bi2h, bh2h, Xi);
    phase2_kernel<<<256, 512, 0, stream>>>(Xi, WT, W2oT, bh2o, thr_h, thr_o,
                                           hm0, hs0, om0, g_mask, g_flag,
                                           spk, osum, nbr);
    filt_kernel<<<512, 256, 0, stream>>>(spk, filt);
    final_kernel<<<1, 256, 0, stream>>>(osum, labels, out);
}